// Round 1
// baseline (2876.361 us; speedup 1.0000x reference)
//
#include <hip/hip_runtime.h>

typedef unsigned short u16;
typedef unsigned int   u32;
typedef short  s16x8 __attribute__((ext_vector_type(8)));
typedef float  f32x4 __attribute__((ext_vector_type(4)));

// ---------- helpers ----------
__device__ __forceinline__ u16 f2bf(float f) {
    u32 u = __builtin_bit_cast(u32, f);
    u += 0x7FFFu + ((u >> 16) & 1u);   // RNE
    return (u16)(u >> 16);
}

__device__ __forceinline__ u32 pk2(int a, int b, float s, float nzs) {
    u32 lo = f2bf(fmaf((float)a, s, nzs));
    u32 hi = f2bf(fmaf((float)b, s, nzs));
    return lo | (hi << 16);
}

__device__ __forceinline__ void gl2lds16(const void* g, void* l) {
    // async global->LDS, 16B/lane, LDS dst = wave-uniform base + lane*16
    __builtin_amdgcn_global_load_lds((const __attribute__((address_space(1))) void*)g,
                                     (__attribute__((address_space(3))) void*)l, 16, 0, 0);
}

#define MFMA16(a, b, c) __builtin_amdgcn_mfma_f32_16x16x32_bf16((a), (b), (c), 0, 0, 0)

// ---------- RMSNorm: f32 [T,4096] -> bf16 [T,4096] ----------
__global__ __launch_bounds__(256)
void rmsnorm_k(const float* __restrict__ x, const float* __restrict__ g, u16* __restrict__ o)
{
    const int t = blockIdx.x;
    const int tid = threadIdx.x;
    const float4* row = (const float4*)(x + (size_t)t * 4096);
    float4 v[4];
    float ss = 0.f;
#pragma unroll
    for (int i = 0; i < 4; ++i) {
        v[i] = row[tid + i * 256];
        ss += v[i].x * v[i].x + v[i].y * v[i].y + v[i].z * v[i].z + v[i].w * v[i].w;
    }
#pragma unroll
    for (int off = 32; off >= 1; off >>= 1) ss += __shfl_xor(ss, off);
    __shared__ float red[4];
    if ((tid & 63) == 0) red[tid >> 6] = ss;
    __syncthreads();
    const float tot = red[0] + red[1] + red[2] + red[3];
    const float rs = rsqrtf(tot * (1.0f / 4096.0f) + 1e-5f);
    const float4* gw = (const float4*)g;
    uint2* orow = (uint2*)(o + (size_t)t * 4096);
#pragma unroll
    for (int i = 0; i < 4; ++i) {
        float4 wv = gw[tid + i * 256];
        uint2 pk;
        pk.x = (u32)f2bf(v[i].x * rs * wv.x) | ((u32)f2bf(v[i].y * rs * wv.y) << 16);
        pk.y = (u32)f2bf(v[i].z * rs * wv.z) | ((u32)f2bf(v[i].w * rs * wv.w) << 16);
        orow[tid + i * 256] = pk;
    }
}

// ---------- W4A16 GEMM: C[M,N] = A[M,K](bf16) x dequant(W[N,K]) ----------
// EPI 0: bf16 store row-major (ldc)
// EPI 1: bf16 store transposed for V: vt[(b*1024+col)*1024 + s]
// EPI 2: f32 store = acc + resid (ldc)
// EPI 3: bf16 store = relu(acc)^2 (ldc)
template<int KDIM, int EPI>
__global__ __launch_bounds__(256)
void gemm_w4(const u16* __restrict__ A, const int* __restrict__ W,
             const float* __restrict__ Sc, const float* __restrict__ Zp,
             void* __restrict__ outp, const float* __restrict__ resid, int ldc)
{
    constexpr int NG = KDIM / 128;
    const int tid = threadIdx.x;
    const int w = tid >> 6, l = tid & 63;
    const int quad = l >> 4, lr = l & 15;
    const int m0 = blockIdx.x << 7, n0 = blockIdx.y << 7;

    __shared__ __align__(16) u16 As[128 * 32];  // [row][k] plain
    __shared__ __align__(16) u16 Bs[128 * 32];  // [o][k], 2-bit xor chunk swizzle

    // A staging (global_load_lds): issue i covers chunks w*128 + i*64 + lane
    const int arow = (w << 5) + (l >> 2);
    const int acol = (l & 3) << 3;
    const u16* Ab0 = A + (size_t)(m0 + arow) * KDIM + acol;
    const u16* Ab1 = Ab0 + (size_t)16 * KDIM;
    u16* AsW0 = &As[w << 10];
    u16* AsW1 = &As[(w << 10) + 512];

    // B staging: thread -> (row br, 16-elem half bco)
    const int br = tid >> 1;
    const int bco = (tid & 1) << 4;
    const int bsw = br & 3;
    const int bc0 = bco >> 3;   // chunk 0 or 2
    const int*   Wb = W + (size_t)(n0 + br) * KDIM + bco;
    const float* Sb = Sc + (size_t)(n0 + br) * NG;
    const float* Zb = Zp + (size_t)(n0 + br) * NG;
    uint4* bd0 = (uint4*)&Bs[br * 32 + (((bc0 + 0) ^ bsw) << 3)];
    uint4* bd1 = (uint4*)&Bs[br * 32 + (((bc0 + 1) ^ bsw) << 3)];

    const int wm = (w >> 1) << 6, wn = (w & 1) << 6;

    f32x4 acc[4][4] = {};

    // prefetch first B tile
    int4 w0, w1, w2, w3;
    {
        const int4* wp = (const int4*)Wb;
        w0 = wp[0]; w1 = wp[1]; w2 = wp[2]; w3 = wp[3];
    }

    for (int kt = 0; kt < KDIM / 32; ++kt) {
        const int k0 = kt << 5;
        __syncthreads();
        gl2lds16(Ab0 + k0, AsW0);
        gl2lds16(Ab1 + k0, AsW1);
        const int g = k0 >> 7;
        const float s = Sb[g];
        const float nzs = -Zb[g] * s;
        uint4 p0, p1;
        p0.x = pk2(w0.x, w0.y, s, nzs); p0.y = pk2(w0.z, w0.w, s, nzs);
        p0.z = pk2(w1.x, w1.y, s, nzs); p0.w = pk2(w1.z, w1.w, s, nzs);
        p1.x = pk2(w2.x, w2.y, s, nzs); p1.y = pk2(w2.z, w2.w, s, nzs);
        p1.z = pk2(w3.x, w3.y, s, nzs); p1.w = pk2(w3.z, w3.w, s, nzs);
        *bd0 = p0; *bd1 = p1;
        if (kt + 1 < KDIM / 32) {  // prefetch next B tile (in flight across compute)
            const int4* wp = (const int4*)(Wb + k0 + 32);
            w0 = wp[0]; w1 = wp[1]; w2 = wp[2]; w3 = wp[3];
        }
        __syncthreads();
        s16x8 af[4], bfr[4];
#pragma unroll
        for (int i = 0; i < 4; ++i)
            af[i] = *(const s16x8*)&As[(wm + i * 16 + lr) * 32 + (quad << 3)];
#pragma unroll
        for (int j = 0; j < 4; ++j) {
            const int rowb = wn + j * 16 + lr;
            bfr[j] = *(const s16x8*)&Bs[rowb * 32 + ((quad ^ (rowb & 3)) << 3)];
        }
#pragma unroll
        for (int i = 0; i < 4; ++i)
#pragma unroll
            for (int j = 0; j < 4; ++j)
                acc[i][j] = MFMA16(af[i], bfr[j], acc[i][j]);
    }

    // epilogue: C row = m0 + wm + i*16 + quad*4 + r ; col = n0 + wn + j*16 + lr
#pragma unroll
    for (int i = 0; i < 4; ++i) {
        const int rr0 = m0 + wm + i * 16 + (quad << 2);
#pragma unroll
        for (int j = 0; j < 4; ++j) {
            const int cc = n0 + wn + j * 16 + lr;
#pragma unroll
            for (int r = 0; r < 4; ++r) {
                const int row = rr0 + r;
                const float v = acc[i][j][r];
                if constexpr (EPI == 0) {
                    ((u16*)outp)[(size_t)row * ldc + cc] = f2bf(v);
                } else if constexpr (EPI == 1) {
                    const int b = row >> 10, sidx = row & 1023;
                    ((u16*)outp)[((size_t)((b << 10) + cc)) * 1024 + sidx] = f2bf(v);
                } else if constexpr (EPI == 2) {
                    ((float*)outp)[(size_t)row * ldc + cc] = v + resid[(size_t)row * ldc + cc];
                } else {
                    const float t = v > 0.f ? v : 0.f;
                    ((u16*)outp)[(size_t)row * ldc + cc] = f2bf(t * t);
                }
            }
        }
    }
}

// ---------- Flash attention (causal, GQA 32q/8kv, HD=128, S=1024) ----------
// Q: bf16 [b*1024+s][4096], K: bf16 [b*1024+s][1024], Vt: bf16 [((b*8+kvh)*128+d)*1024 + s]
// O: bf16 [b*1024+s][4096]
__global__ __launch_bounds__(256)
void attn_k(const u16* __restrict__ Q, const u16* __restrict__ K,
            const u16* __restrict__ Vt, u16* __restrict__ O)
{
    const int qt = blockIdx.x, h = blockIdx.y, b = blockIdx.z;
    const int kh = h >> 2;
    const int tid = threadIdx.x, w = tid >> 6, l = tid & 63;
    const int quad = l >> 4, lr = l & 15;
    const int q0 = qt << 6;

    __shared__ __align__(16) u16 Qs[64 * 128];  // xor-swizzled chunks (16 chunks/row)
    __shared__ __align__(16) u16 Ks[64 * 128];
    __shared__ __align__(16) u16 Vs[128 * 64];  // Vt tile [d][n], 8 chunks/row swizzled
    __shared__ __align__(16) u16 Ps[64 * 72];   // P round-trip, padded stride 72

    // stage Q tile once
#pragma unroll
    for (int i = 0; i < 4; ++i) {
        const int L = i * 256 + w * 64 + l;
        const int row = L >> 4, cl = L & 15;
        const int c = cl ^ (row & 15);
        gl2lds16(Q + ((size_t)(b * 1024 + q0 + row) * 4096 + h * 128 + c * 8),
                 &Qs[(i * 256 + w * 64) * 8]);
    }
    __syncthreads();
    s16x8 qf[4];
#pragma unroll
    for (int ks = 0; ks < 4; ++ks) {
        const int rq = w * 16 + lr;
        const int c = ks * 4 + quad;
        qf[ks] = *(const s16x8*)&Qs[rq * 128 + ((c ^ (rq & 15)) << 3)];
    }

    float m_i[4] = {-__builtin_inff(), -__builtin_inff(), -__builtin_inff(), -__builtin_inff()};
    float l_i[4] = {0.f, 0.f, 0.f, 0.f};
    f32x4 oa[8] = {};

    for (int n0 = 0; n0 <= q0; n0 += 64) {
        __syncthreads();
#pragma unroll
        for (int i = 0; i < 4; ++i) {
            const int L = i * 256 + w * 64 + l;
            const int row = L >> 4, cl = L & 15;
            const int c = cl ^ (row & 15);
            gl2lds16(K + ((size_t)(b * 1024 + n0 + row) * 1024 + kh * 128 + c * 8),
                     &Ks[(i * 256 + w * 64) * 8]);
        }
#pragma unroll
        for (int i = 0; i < 4; ++i) {
            const int L = i * 256 + w * 64 + l;
            const int d = L >> 3, cl = L & 7;
            const int c = cl ^ (d & 7);
            gl2lds16(Vt + ((size_t)((b * 8 + kh) * 128 + d) * 1024 + n0 + c * 8),
                     &Vs[(i * 256 + w * 64) * 8]);
        }
        __syncthreads();

        // S = Q K^T
        f32x4 sc[4] = {};
#pragma unroll
        for (int ks = 0; ks < 4; ++ks) {
#pragma unroll
            for (int ni = 0; ni < 4; ++ni) {
                const int n = ni * 16 + lr;
                const int c = ks * 4 + quad;
                s16x8 bk = *(const s16x8*)&Ks[n * 128 + ((c ^ (n & 15)) << 3)];
                sc[ni] = MFMA16(qf[ks], bk, sc[ni]);
            }
        }
        const float scale = 0.08838834764831845f;  // 1/sqrt(128)
        const bool diag = (n0 == q0);
#pragma unroll
        for (int ni = 0; ni < 4; ++ni) {
            const int nabs = n0 + ni * 16 + lr;
#pragma unroll
            for (int r = 0; r < 4; ++r) {
                float vv = sc[ni][r] * scale;
                if (diag && nabs > q0 + w * 16 + quad * 4 + r) vv = -__builtin_inff();
                sc[ni][r] = vv;
            }
        }
        float alpha[4];
#pragma unroll
        for (int r = 0; r < 4; ++r) {
            float mx = fmaxf(fmaxf(sc[0][r], sc[1][r]), fmaxf(sc[2][r], sc[3][r]));
            mx = fmaxf(mx, __shfl_xor(mx, 1));
            mx = fmaxf(mx, __shfl_xor(mx, 2));
            mx = fmaxf(mx, __shfl_xor(mx, 4));
            mx = fmaxf(mx, __shfl_xor(mx, 8));
            const float mn = fmaxf(m_i[r], mx);
            alpha[r] = __expf(m_i[r] - mn);
            m_i[r] = mn;
#pragma unroll
            for (int ni = 0; ni < 4; ++ni) sc[ni][r] = __expf(sc[ni][r] - mn);
            float sr = sc[0][r] + sc[1][r] + sc[2][r] + sc[3][r];
            sr += __shfl_xor(sr, 1); sr += __shfl_xor(sr, 2);
            sr += __shfl_xor(sr, 4); sr += __shfl_xor(sr, 8);
            l_i[r] = l_i[r] * alpha[r] + sr;
        }
#pragma unroll
        for (int dt = 0; dt < 8; ++dt)
#pragma unroll
            for (int r = 0; r < 4; ++r) oa[dt][r] *= alpha[r];
        // P -> LDS (C-layout scatter), then re-read in A-layout
#pragma unroll
        for (int ni = 0; ni < 4; ++ni)
#pragma unroll
            for (int r = 0; r < 4; ++r)
                Ps[(w * 16 + quad * 4 + r) * 72 + ni * 16 + lr] = f2bf(sc[ni][r]);
        __syncthreads();
#pragma unroll
        for (int ks = 0; ks < 2; ++ks) {
            s16x8 pa = *(const s16x8*)&Ps[(w * 16 + lr) * 72 + ks * 32 + (quad << 3)];
#pragma unroll
            for (int dt = 0; dt < 8; ++dt) {
                const int d = dt * 16 + lr;
                const int c = ks * 4 + quad;
                s16x8 bv = *(const s16x8*)&Vs[(d << 6) + ((c ^ (d & 7)) << 3)];
                oa[dt] = MFMA16(pa, bv, oa[dt]);
            }
        }
    }
#pragma unroll
    for (int dt = 0; dt < 8; ++dt) {
#pragma unroll
        for (int r = 0; r < 4; ++r) {
            const int row = q0 + w * 16 + quad * 4 + r;
            const int col = h * 128 + dt * 16 + lr;
            O[(size_t)(b * 1024 + row) * 4096 + col] = f2bf(oa[dt][r] / l_i[r]);
        }
    }
}

// ---------- launch ----------
extern "C" void kernel_launch(void* const* d_in, const int* in_sizes, int n_in,
                              void* d_out, int out_size, void* d_ws, size_t ws_size,
                              hipStream_t stream)
{
    (void)in_sizes; (void)n_in; (void)out_size; (void)ws_size;
    const float* hidden = (const float*)d_in[0];
    const float* ln1 = (const float*)d_in[1];
    const float* ln2 = (const float*)d_in[2];
    const int*   q_qw = (const int*)d_in[3];
    const float* q_s  = (const float*)d_in[4];
    const float* q_z  = (const float*)d_in[5];
    const int*   k_qw = (const int*)d_in[6];
    const float* k_s  = (const float*)d_in[7];
    const float* k_z  = (const float*)d_in[8];
    const int*   v_qw = (const int*)d_in[9];
    const float* v_s  = (const float*)d_in[10];
    const float* v_z  = (const float*)d_in[11];
    const int*   o_qw = (const int*)d_in[12];
    const float* o_s  = (const float*)d_in[13];
    const float* o_z  = (const float*)d_in[14];
    const int*   up_qw = (const int*)d_in[15];
    const float* up_s  = (const float*)d_in[16];
    const float* up_z  = (const float*)d_in[17];
    const int*   dn_qw = (const int*)d_in[18];
    const float* dn_s  = (const float*)d_in[19];
    const float* dn_z  = (const float*)d_in[20];
    float* out = (float*)d_out;
    char* ws = (char*)d_ws;

    // ws layout (needs ~109 MB total):
    float* x_buf  = (float*)(ws);                 // 33,554,432 B  f32 [2048][4096]
    u16* h_buf    = (u16*)(ws + 33554432);        // 16,777,216 B  bf16 (reused as h2)
    u16* q_buf    = (u16*)(ws + 50331648);        // 16,777,216 B
    u16* k_buf    = (u16*)(ws + 67108864);        //  4,194,304 B
    u16* vt_buf   = (u16*)(ws + 71303168);        //  4,194,304 B
    u16* attn_buf = (u16*)(ws + 75497472);        // 16,777,216 B
    u16* act_buf  = (u16*)(ws + 50331648);        // 58,720,256 B (overlays q/k/vt/attn, MLP phase)
    u16* h2_buf   = h_buf;

    rmsnorm_k<<<2048, 256, 0, stream>>>(hidden, ln1, h_buf);
    gemm_w4<4096, 0><<<dim3(16, 32),  256, 0, stream>>>(h_buf, q_qw, q_s, q_z, (void*)q_buf,  nullptr, 4096);
    gemm_w4<4096, 0><<<dim3(16, 8),   256, 0, stream>>>(h_buf, k_qw, k_s, k_z, (void*)k_buf,  nullptr, 1024);
    gemm_w4<4096, 1><<<dim3(16, 8),   256, 0, stream>>>(h_buf, v_qw, v_s, v_z, (void*)vt_buf, nullptr, 1024);
    attn_k<<<dim3(16, 32, 2), 256, 0, stream>>>(q_buf, k_buf, vt_buf, attn_buf);
    gemm_w4<4096, 2><<<dim3(16, 32),  256, 0, stream>>>(attn_buf, o_qw, o_s, o_z, (void*)x_buf, hidden, 4096);
    rmsnorm_k<<<2048, 256, 0, stream>>>(x_buf, ln2, h2_buf);
    gemm_w4<4096, 3><<<dim3(16, 112), 256, 0, stream>>>(h2_buf, up_qw, up_s, up_z, (void*)act_buf, nullptr, 14336);
    gemm_w4<14336, 2><<<dim3(16, 32), 256, 0, stream>>>(act_buf, dn_qw, dn_s, dn_z, (void*)out, x_buf, 4096);
}